// Round 19
// baseline (149.620 us; speedup 1.0000x reference)
//
#include <hip/hip_runtime.h>
#include <math.h>

// Problem constants (match reference)
#define N_ATOMS 256
#define N_FEAT  128
#define BATCH   8
#define BINS    300
#define INV_STEP 149.5f        // 1/STEP, STEP = 2/(BINS-1)
#define ONE_OVER_2PI 0.15915494309189535f
#define INV_112 0.8928571428571429f   // 1/1.12
#define WIN 2                  // bins beyond |d|=2 contribute < exp(-9)*|basis| ~ 1e-5 << tol
#define WINW 5                 // 2*WIN+1
#define NHIST 4                // privatized histogram copies per node
#define EXPM2 0.13533528323661270f    // e^-2

struct V3 { float x, y, z; };
__device__ __forceinline__ V3 v3sub(V3 a, V3 b) { return {a.x-b.x, a.y-b.y, a.z-b.z}; }
__device__ __forceinline__ float v3dot(V3 a, V3 b) { return a.x*b.x + a.y*b.y + a.z*b.z; }
__device__ __forceinline__ V3 v3cross(V3 a, V3 b) {
    return {a.y*b.z - a.z*b.y, a.z*b.x - a.x*b.z, a.x*b.y - a.y*b.x};
}
__device__ __forceinline__ float clamp1(float x) { return fminf(1.0f, fmaxf(-1.0f, x)); }

// Branchless Cephes asinf: |x|<=0.5 poly; else pi/2 - 2*asin(sqrt((1-|x|)/2)).
__device__ __forceinline__ float asin_fast(float x) {
    float u = fabsf(x);
    bool big = u > 0.5f;
    float z = big ? 0.5f * (1.0f - u) : u * u;
    float s = big ? __builtin_amdgcn_sqrtf(z) : u;  // v_sqrt_f32
    float p = fmaf(z, 4.2163199048e-2f, 2.4181311049e-2f);
    p = fmaf(z, p, 4.5470025998e-2f);
    p = fmaf(z, p, 7.4953002686e-2f);
    p = fmaf(z, p, 1.6666752422e-1f);
    float r = fmaf(s * z, p, s);
    r = big ? (1.5707963267948966f - 2.0f * r) : r;
    return copysignf(r, x);
}

// writhe of segment pair (i,i+1),(j,j+1) from float4-padded LDS coords.
// Direction normalization algebraically removed (4 rsq instead of 8).
__device__ __forceinline__ float writhe_ij(const float4* cs, int i, int j) {
    const float4 qi  = cs[i],   qi1 = cs[i + 1];
    const float4 qj  = cs[j],   qj1 = cs[j + 1];
    V3 pi  = {qi.x,  qi.y,  qi.z};
    V3 pi1 = {qi1.x, qi1.y, qi1.z};
    V3 pj  = {qj.x,  qj.y,  qj.z};
    V3 pj1 = {qj1.x, qj1.y, qj1.z};

    V3 u0 = v3sub(pj,  pi);
    V3 u1 = v3sub(pj1, pi);
    V3 u2 = v3sub(pj,  pi1);
    V3 u3 = v3sub(pj1, pi1);

    V3 c0 = v3cross(u0, u1);
    V3 c1 = v3cross(u1, u3);
    V3 c2 = v3cross(u3, u2);
    V3 c3 = v3cross(u2, u0);

    float r0 = __builtin_amdgcn_rsqf(v3dot(c0, c0));
    float r1 = __builtin_amdgcn_rsqf(v3dot(c1, c1));
    float r2 = __builtin_amdgcn_rsqf(v3dot(c2, c2));
    float r3 = __builtin_amdgcn_rsqf(v3dot(c3, c3));

    float omega = asin_fast(clamp1(v3dot(c0, c1) * (r0 * r1)))
                + asin_fast(clamp1(v3dot(c1, c2) * (r1 * r2)))
                + asin_fast(clamp1(v3dot(c2, c3) * (r2 * r3)))
                + asin_fast(clamp1(v3dot(c3, c0) * (r3 * r0)));

    float sg = v3dot(v3cross(v3sub(pj1, pj), v3sub(pi1, pi)), u0);
    float sign = (sg > 0.0f) ? 1.0f : ((sg < 0.0f) ? -1.0f : 0.0f);
    return omega * sign * ONE_OVER_2PI;
}

// edge -> (g, pp, k0) for node tau, edge index ee (branchless)
__device__ __forceinline__ void edge_compute(const float4* cs, int tau, int ee,
                                             float& g, float& pp, int& k0) {
    const int eT1 = (tau <= N_ATOMS - 2) ? tau - 1 : 0;
    const int typ = (ee < eT1) ? 0 : 1;
    const int a = (typ == 0) ? ee : ee - eT1 + 1;

    const float4 qa = cs[a];
    const float4 qt = cs[tau];
    const float dx = qa.x - qt.x;
    const float dy = qa.y - qt.y;
    const float dz = qa.z - qt.z;
    g = __expf(-(dx*dx + dy*dy + dz*dz));

    const float w = writhe_ij(cs, a - typ, tau - typ);
    pp = (w + 1.0f) * INV_STEP;          // pp - k = (w - c_k)/STEP
    k0 = __float2int_rn(pp);
}

__device__ __forceinline__ void deposit(float* h2, int base, float g, float pp, int k0) {
    const int klo = k0 - WIN;
    float d = pp - (float)klo;
    float e = g * __expf(-d * d);
    float u = __expf(2.0f * d - 1.0f);
    #pragma unroll
    for (int m = 0; m < WINW; ++m) {
        const int k = klo + m;
        if (k >= 0 && k < BINS) atomicAdd(&h2[base + k], e);
        e *= u;
        u *= EXPM2;
    }
}

// One 128-thread block per NODE PAIR (t0, t1) = (p+2, 255-p), same batch.
// 4 edges/thread: e = tid, tid+128, tid+256, tid+384 (e>=256 is ALWAYS node1
// since E0 <= 253) -> 4 independent writhe chains per thread for ILP.
// Same 5-barrier phase structure as the round-17 champion (r18's fused
// mega-region regressed: compiler scheduling, not barrier count, dominated).
__global__ __launch_bounds__(128) void fused_kernel(const float* __restrict__ coords,
                                                    const float* __restrict__ nf,
                                                    const float* __restrict__ basis,
                                                    float* __restrict__ out) {
    const int blk = blockIdx.x;
    const int b = blk & 7;
    const int p = blk >> 3;            // pair index 0..126
    const int t0 = p + 2;              // 2..128
    const int t1 = 255 - p;            // 255..129
    const int tid = threadIdx.x;       // 0..127

    const int E0  = 2 * t0 - 3;                         // edges of node t0 (<=253)
    const int E1n = (t1 == 255) ? 253 : 2 * t1 - 3;     // edges of node t1
    const int E = E0 + E1n;                             // 508 (254 when p==0)

    // prefetch nf: thread owns feature tid for BOTH rows
    const float mynf0 = nf[((size_t)((b << 8) | t0)) * N_FEAT + tid];
    const float mynf1 = nf[((size_t)((b << 8) | t1)) * N_FEAT + tid];

    __shared__ float4 cs[N_ATOMS];           // 4 KB, padded xyz0
    __shared__ float h2[2 * NHIST * BINS];   // 9.6 KB (two 4-copy histograms)
    __shared__ float sden[2];
    __shared__ int skmin[2], skmax[2];

    {
        const int g0 = ((b << 8) + tid) * 3;
        const int g1 = ((b << 8) + tid + 128) * 3;
        cs[tid]       = make_float4(coords[g0], coords[g0 + 1], coords[g0 + 2], 0.0f);
        cs[tid + 128] = make_float4(coords[g1], coords[g1 + 1], coords[g1 + 2], 0.0f);
    }
    if (tid < 2) { sden[tid] = 0.0f; skmin[tid] = BINS - 1; skmax[tid] = 0; }
    __syncthreads();                         // BARRIER 1

    // ---- four independent edge computations (branchless; ILP) ----
    const int e1 = tid, e2 = tid + 128, e3 = tid + 256, e4 = tid + 384;
    const bool a1 = (e1 < E), a2 = (e2 < E), a3 = (e3 < E), a4 = (e4 < E);
    const int n1 = (e1 < E0) ? 0 : 1;
    const int n2 = (e2 < E0) ? 0 : 1;
    const int ee1 = n1 ? min(e1 - E0, E1n - 1) : e1;
    const int ee2 = n2 ? min(e2 - E0, E1n - 1) : e2;
    const int ee3 = min(e3 - E0, E1n - 1);   // e3,e4 always node1
    const int ee4 = min(e4 - E0, E1n - 1);

    float g1v, pp1; int k01;
    float g2v, pp2; int k02;
    float g3v, pp3; int k03;
    float g4v, pp4; int k04;
    edge_compute(cs, n1 ? t1 : t0, ee1, g1v, pp1, k01);
    edge_compute(cs, n2 ? t1 : t0, ee2, g2v, pp2, k02);
    edge_compute(cs, t1, ee3, g3v, pp3, k03);
    edge_compute(cs, t1, ee4, g4v, pp4, k04);

    // ---- per-node range + denominator reduction ----
    float d0 = ((a1 && n1 == 0) ? g1v : 0.0f) + ((a2 && n2 == 0) ? g2v : 0.0f);
    float d1 = ((a1 && n1 == 1) ? g1v : 0.0f) + ((a2 && n2 == 1) ? g2v : 0.0f)
             + (a3 ? g3v : 0.0f) + (a4 ? g4v : 0.0f);
    int kn0 = BINS - 1, kx0 = 0, kn1 = BINS - 1, kx1 = 0;
    if (a1) {
        const int kmn = max(0, k01 - WIN), kmx = min(BINS - 1, k01 + WIN);
        if (n1 == 0) { kn0 = kmn; kx0 = kmx; } else { kn1 = kmn; kx1 = kmx; }
    }
    if (a2) {
        const int kmn = max(0, k02 - WIN), kmx = min(BINS - 1, k02 + WIN);
        if (n2 == 0) { kn0 = min(kn0, kmn); kx0 = max(kx0, kmx); }
        else         { kn1 = min(kn1, kmn); kx1 = max(kx1, kmx); }
    }
    if (a3) { kn1 = min(kn1, max(0, k03 - WIN)); kx1 = max(kx1, min(BINS - 1, k03 + WIN)); }
    if (a4) { kn1 = min(kn1, max(0, k04 - WIN)); kx1 = max(kx1, min(BINS - 1, k04 + WIN)); }

    #pragma unroll
    for (int off = 32; off > 0; off >>= 1) {
        d0 += __shfl_xor(d0, off, 64);
        d1 += __shfl_xor(d1, off, 64);
        kn0 = min(kn0, __shfl_xor(kn0, off, 64));
        kx0 = max(kx0, __shfl_xor(kx0, off, 64));
        kn1 = min(kn1, __shfl_xor(kn1, off, 64));
        kx1 = max(kx1, __shfl_xor(kx1, off, 64));
    }
    if ((tid & 63) == 0) {
        atomicAdd(&sden[0], d0);
        atomicAdd(&sden[1], d1);
        atomicMin(&skmin[0], kn0);
        atomicMax(&skmax[0], kx0);
        atomicMin(&skmin[1], kn1);
        atomicMax(&skmax[1], kx1);
    }
    __syncthreads();                         // BARRIER 2

    // ---- lazy zero: touched range of all copies, both nodes ----
    {
        const int nu = tid >> 6;             // 64 threads per node
        const int l = tid & 63;
        const int kmin = skmin[nu], kmax = skmax[nu];
        const int base = nu * NHIST * BINS;
        for (int k = kmin + l; k <= kmax; k += 64) {
            #pragma unroll
            for (int c = 0; c < NHIST; ++c) h2[base + c * BINS + k] = 0.0f;
        }
    }
    __syncthreads();                         // BARRIER 3

    // ---- deposits (exp-recurrence, g folded into seed) ----
    const int copy = tid & (NHIST - 1);
    if (a1) deposit(h2, (n1 * NHIST + copy) * BINS, g1v, pp1, k01);
    if (a2) deposit(h2, (n2 * NHIST + copy) * BINS, g2v, pp2, k02);
    if (a3) deposit(h2, (NHIST + copy) * BINS, g3v, pp3, k03);
    if (a4) deposit(h2, (NHIST + copy) * BINS, g4v, pp4, k04);
    __syncthreads();                         // BARRIER 4

    // ---- combine the 4 copies per node, touched range only ----
    {
        const int nu = tid >> 6;
        const int kmin = skmin[nu], kmax = skmax[nu];
        const int base = nu * NHIST * BINS;
        for (int k = kmin + (tid & 63); k <= kmax; k += 64) {
            h2[base + k] = h2[base + k] + h2[base + BINS + k]
                         + h2[base + 2 * BINS + k] + h2[base + 3 * BINS + k];
        }
    }
    __syncthreads();                         // BARRIER 5

    // ---- projection + direct write: thread owns feature tid, both nodes ----
    {
        float acc0 = 0.0f, acc1 = 0.0f;
        {
            const int kmin = skmin[0], kmax = skmax[0];
            for (int k = kmin; k <= kmax; ++k)
                acc0 = fmaf(h2[k], basis[k * N_FEAT + tid], acc0);
        }
        {
            const int kmin = skmin[1], kmax = skmax[1];
            const int base = NHIST * BINS;
            for (int k = kmin; k <= kmax; ++k)
                acc1 = fmaf(h2[base + k], basis[k * N_FEAT + tid], acc1);
        }
        out[((size_t)((b << 8) | t0)) * N_FEAT + tid] = mynf0 + acc0 * (INV_112 / sden[0]);
        out[((size_t)((b << 8) | t1)) * N_FEAT + tid] = mynf1 + acc1 * (INV_112 / sden[1]);
    }
    if (p == 0) {
        // passthrough rows t = 0, 1 (no incoming edges), from the (2,255) block
        const size_t i0 = ((size_t)(b << 8)) * N_FEAT + tid;
        const size_t i1 = ((size_t)((b << 8) | 1)) * N_FEAT + tid;
        out[i0] = nf[i0];
        out[i1] = nf[i1];
    }
}

extern "C" void kernel_launch(void* const* d_in, const int* in_sizes, int n_in,
                              void* d_out, int out_size, void* d_ws, size_t ws_size,
                              hipStream_t stream) {
    const float* coords = (const float*)d_in[0];   // (B*N, 3) f32
    const float* nf     = (const float*)d_in[1];   // (B*N, 128) f32
    const float* basis  = (const float*)d_in[2];   // (300, 128) f32
    float* out = (float*)d_out;                    // (B*N, 128) f32

    fused_kernel<<<BATCH * 127, 128, 0, stream>>>(coords, nf, basis, out);
}